// Round 21
// baseline (95.249 us; speedup 1.0000x reference)
//
#include <hip/hip_runtime.h>
#include <hip/hip_bf16.h>
#include <cstddef>
#include <cstdint>

#define CCH 256   // channels
#define DQK 32    // q/k channels
#define NPX 4096  // H*W
#define BQK 256   // queries per block (16 waves x 16-query softmax strips)
#define BM  64    // key tile per iteration
#define NB  4     // batch
#define NW  16    // waves per block

typedef __attribute__((ext_vector_type(8))) short bf16x8;    // 8 bf16 (MFMA A/B frag)
typedef __attribute__((ext_vector_type(4))) float f32x4;     // 16x16 MFMA C/D
typedef __attribute__((ext_vector_type(16))) float f32x16;   // 32x32 MFMA C/D
typedef __attribute__((ext_vector_type(4))) unsigned int u32x4;

#if __has_builtin(__builtin_amdgcn_exp2f)
#define EXP2F(x) __builtin_amdgcn_exp2f(x)
#else
#define EXP2F(x) exp2f(x)
#endif

__device__ inline unsigned short f2bf(float f) {            // RNE float->bf16
    unsigned u = __builtin_bit_cast(unsigned, f);
    u += 0x7FFFu + ((u >> 16) & 1u);
    return (unsigned short)(u >> 16);
}
__device__ inline float bf2f(unsigned short h) {
    unsigned u = (unsigned)h << 16;
    return __builtin_bit_cast(float, u);
}
__device__ inline unsigned pkbf(float a, float b) {         // v_cvt_pk_bf16_f32
    __hip_bfloat162 h = __float22bfloat162_rn(make_float2(a, b));
    unsigned u;
    __builtin_memcpy(&u, &h, 4);                            // a in low 16 bits
    return u;
}

// ---------------------------------------------------------------------------
// convert_kernel (unchanged): W -> bf16, Wq/bq scaled by log2(e).
// ---------------------------------------------------------------------------
__global__ __launch_bounds__(256) void convert_kernel(
    const float* __restrict__ Wq, const float* __restrict__ bq,
    const float* __restrict__ Wk, const float* __restrict__ bk,
    const float* __restrict__ Wv, const float* __restrict__ bv,
    unsigned short* __restrict__ Wb, float* __restrict__ bb)
{
    const float LOG2E = 1.4426950408889634f;
    const int o = blockIdx.x;
    const int c = threadIdx.x;
    float v;
    if (o < 32)       v = Wq[o * CCH + c] * LOG2E;
    else if (o < 64)  v = Wk[(o - 32) * CCH + c];
    else              v = Wv[(o - 64) * CCH + c];
    Wb[o * CCH + c] = f2bf(v);
    if (c == 0)
        bb[o] = (o < 32) ? bq[o] * LOG2E : (o < 64) ? bk[o - 32] : bv[o - 64];
}

// ---------------------------------------------------------------------------
// proj_mfma (unchanged — verified)
// ---------------------------------------------------------------------------
__global__ __launch_bounds__(512) void proj_mfma(
    const float* __restrict__ x,
    const unsigned short* __restrict__ Wb, const float* __restrict__ bb,
    unsigned short* __restrict__ ws)
{
    __shared__ __align__(16) unsigned short xT[64][264];   // 33 KB

    const int tid  = threadIdx.x;
    const int lane = tid & 63;
    const int w    = tid >> 6;
    const int ln   = lane & 15;
    const int g    = lane >> 4;
    const int bid  = blockIdx.x;

    const int xcd  = bid & 7;
    const int idx  = bid >> 3;             // 0..159
    const int slab = xcd + 8 * (idx / 5);  // 0..255
    const int ocg  = idx % 5;
    const int b    = slab >> 6;
    const int pxt  = slab & 63;
    const int pxg0 = pxt * 64;

    const int mt    = w >> 1;
    const int ocrow = ocg * 64 + mt * 16 + ln;
    bf16x8 a[8];
#pragma unroll
    for (int k8 = 0; k8 < 8; ++k8)
        a[k8] = *(const bf16x8*)(Wb + (size_t)ocrow * CCH + k8 * 32 + g * 8);

    {
        const int pxl = (tid & 15) * 4;
        const int c0  = (tid >> 4) * 8;
        float4 xv[8];
#pragma unroll
        for (int cc = 0; cc < 8; ++cc)
            xv[cc] = *(const float4*)(x + ((size_t)(b * CCH + c0 + cc)) * NPX + pxg0 + pxl);
#pragma unroll
        for (int j = 0; j < 4; ++j) {
            unsigned u[4];
#pragma unroll
            for (int h = 0; h < 4; ++h) {
                const float f0 = ((const float*)&xv[2 * h])[j];
                const float f1 = ((const float*)&xv[2 * h + 1])[j];
                u[h] = pkbf(f0, f1);
            }
            *(u32x4*)&xT[pxl + j][c0] = (u32x4){u[0], u[1], u[2], u[3]};
        }
    }
    __syncthreads();

    const int nt0 = (w & 1) * 2;
    const float4 bb4 = *(const float4*)(bb + ocg * 64 + mt * 16 + g * 4);
    f32x4 acc0 = (f32x4){bb4.x, bb4.y, bb4.z, bb4.w};
    f32x4 acc1 = acc0;
#pragma unroll
    for (int k8 = 0; k8 < 8; ++k8) {
        const bf16x8 b0 = *(const bf16x8*)&xT[nt0 * 16 + ln][k8 * 32 + g * 8];
        const bf16x8 b1 = *(const bf16x8*)&xT[nt0 * 16 + 16 + ln][k8 * 32 + g * 8];
        acc0 = __builtin_amdgcn_mfma_f32_16x16x32_bf16(a[k8], b0, acc0, 0, 0, 0);
        acc1 = __builtin_amdgcn_mfma_f32_16x16x32_bf16(a[k8], b1, acc1, 0, 0, 0);
    }

    unsigned short* qT = ws;
    unsigned short* kT = ws + (size_t)NB * NPX * 32;
    unsigned short* vb = ws + (size_t)2 * NB * NPX * 32;
#pragma unroll
    for (int j = 0; j < 2; ++j) {
        const f32x4 acc = j ? acc1 : acc0;
        const int px = pxg0 + (nt0 + j) * 16 + ln;
        if (ocg == 0) {
            const unsigned lo = pkbf(acc[0], acc[1]);
            const unsigned hi = pkbf(acc[2], acc[3]);
            unsigned short* dst = (mt < 2)
                ? qT + ((size_t)b * NPX + px) * 32 + mt * 16 + g * 4
                : kT + ((size_t)b * NPX + px) * 32 + (mt - 2) * 16 + g * 4;
            *(uint2*)dst = make_uint2(lo, hi);
        } else {
            const int c_row = (ocg - 1) * 64 + mt * 16 + g * 4;
#pragma unroll
            for (int rr = 0; rr < 4; ++rr)
                vb[((size_t)(b * CCH + c_row + rr)) * NPX + px] = f2bf(acc[rr]);
        }
    }
}

// ---------------------------------------------------------------------------
// Flash attention R21: LDS-BW-bound fix. PV on mfma_f32_32x32x16_bf16:
// wave = (qg=w&3, cg=w>>2) owns 64q x 64c as 2x2 32-tiles (64 AGPR).
// Per kc: 2 P-frags + 2 V-frags (4 ds_read_b128) -> 4 MFMA32; LDS reads
// halve (512->256 KB/iter/CU). V staged to LDS via global_load_lds with
// pre-swizzled source (DMA issued post-barrier during PV; vmcnt(0) at the
// next barrier). E/softmax/P-pack (16x16, exp2, defer-max) unchanged.
// ---------------------------------------------------------------------------
__global__ __launch_bounds__(1024, 4) void attn_kernel(
    const unsigned short* __restrict__ qT, const unsigned short* __restrict__ kT,
    const unsigned short* __restrict__ vB, const float* __restrict__ x,
    const float* __restrict__ gamma, float* __restrict__ out,
    unsigned short* __restrict__ opart, float* __restrict__ mlm,
    float* __restrict__ mll, int ns)
{
    __shared__ __align__(16) unsigned short Pl[2][BQK * 64];  // 64KB, XOR swz
    __shared__ __align__(16) unsigned short Vl[2][CCH * 64];  // 64KB, XOR swz
    __shared__ __align__(16) unsigned short Kl[2][64 * 32];   // 8KB K stage
    __shared__ float scb[2][BQK];
    __shared__ int   flg[2][NW];
    __shared__ float l_lds[BQK];

    const int tid  = threadIdx.x;
    const int lane = tid & 63;
    const int w    = tid >> 6;       // wave 0..15
    const int ln   = lane & 15;
    const int g    = lane >> 4;      // 16-lane group 0..3 (softmax side)
    const int l32  = lane & 31;      // 32x32 col
    const int h32  = lane >> 5;      // 32x32 k-half
    const int bid  = blockIdx.x;

    const int b    = (bid & 7) >> 1;                        // batch -> XCD pair
    const int jb   = ((bid >> 3) << 1) | (bid & 1);         // job in batch
    const int tile = jb / ns;
    const int s    = jb - tile * ns;
    const int n0   = tile * BQK;

    const int qg = w & 3;    // PV q-group (64 q)
    const int cg = w >> 2;   // PV c-group (64 c)

    const bf16x8 qf = *(const bf16x8*)(qT + ((size_t)b * NPX + n0 + w * 16 + ln) * 32 + g * 8);

    f32x16 acc2[2][2];       // [qt2][ct2] 32x32 tiles -> 64 AGPR
#pragma unroll
    for (int a0 = 0; a0 < 2; ++a0)
#pragma unroll
        for (int a1 = 0; a1 < 2; ++a1)
#pragma unroll
            for (int i = 0; i < 16; ++i) acc2[a0][a1][i] = 0.f;
    float mreg = -INFINITY, lreg = 0.f;

    const unsigned short* kTb = kT + (size_t)b * NPX * 32;
    const unsigned short* vBb = vB + (size_t)b * CCH * NPX;
    const int kbase = s * (NPX / ns);
    const int iters = NPX / (ns * BM);
    const unsigned swz   = ((unsigned)lane & 7u) << 4;
    const unsigned myrow = (unsigned)(w * 16 + ln) * 128u;
    const float THR2 = 11.544655f;   // 8 * log2(e)
    const int vko = ((lane & 7) ^ ((lane >> 3) & 7)) * 8;   // pre-swizzled V src k-off

    // ---- prologue: stage K(0) and V(0)
    if (w < 4) {
        const unsigned short* ksrc = kTb + (size_t)kbase * 32 + w * 512 + lane * 8;
        __builtin_amdgcn_global_load_lds(
            (const __attribute__((address_space(1))) void*)ksrc,
            (__attribute__((address_space(3))) void*)&Kl[0][w * 512], 16, 0, 0);
    }
#pragma unroll
    for (int i = 0; i < 2; ++i) {
        const unsigned short* vsrc = vBb + (size_t)(w * 16 + i * 8 + (lane >> 3)) * NPX + kbase + vko;
        __builtin_amdgcn_global_load_lds(
            (const __attribute__((address_space(1))) void*)vsrc,
            (__attribute__((address_space(3))) void*)&Vl[0][(w * 16 + i * 8) * 64], 16, 0, 0);
    }
    asm volatile("s_waitcnt vmcnt(0)" ::: "memory");
    __syncthreads();

    for (int t = 0; t < iters; ++t) {
        const int m0 = kbase + t * BM;
        const int mnext = (t + 1 < iters) ? (m0 + BM) : m0;
        const int nbuf = (t + 1) & 1;

        // ---- K(t+1) DMA (waves 0-3); drains at this iter's barrier
        if (w < 4) {
            const unsigned short* ksrc = kTb + (size_t)mnext * 32 + w * 512 + lane * 8;
            __builtin_amdgcn_global_load_lds(
                (const __attribute__((address_space(1))) void*)ksrc,
                (__attribute__((address_space(3))) void*)&Kl[nbuf][w * 512], 16, 0, 0);
        }

        // ---- E from LDS-staged K (16x16, unchanged)
        const unsigned short* kl = &Kl[t & 1][0];
        f32x4 e[4];
#pragma unroll
        for (int s4 = 0; s4 < 4; ++s4) {
            const bf16x8 ka = *(const bf16x8*)(kl + (s4 * 16 + ln) * 32 + g * 8);
            e[s4] = __builtin_amdgcn_mfma_f32_16x16x32_bf16(
                        ka, qf, (f32x4){0.f, 0.f, 0.f, 0.f}, 0, 0, 0);
        }

        // ---- exp2-domain online softmax with defer-max (unchanged)
        float lm = -INFINITY;
#pragma unroll
        for (int s4 = 0; s4 < 4; ++s4)
#pragma unroll
            for (int rr = 0; rr < 4; ++rr) lm = fmaxf(lm, e[s4][rr]);
        lm = fmaxf(lm, __shfl_xor(lm, 16));
        lm = fmaxf(lm, __shfl_xor(lm, 32));
        const float mnew = (lm <= mreg + THR2) ? mreg : lm;
        const float sc   = EXP2F(mreg - mnew);
        float ps = 0.f;
#pragma unroll
        for (int s4 = 0; s4 < 4; ++s4)
#pragma unroll
            for (int rr = 0; rr < 4; ++rr) {
                const float p = EXP2F(e[s4][rr] - mnew);
                e[s4][rr] = p;
                ps += p;
            }
        ps += __shfl_xor(ps, 16);
        ps += __shfl_xor(ps, 32);
        lreg = lreg * sc + ps;
        mreg = mnew;

        // ---- P pack -> Pl[t&1] (XOR swizzled rows, unchanged)
        const int bw = t & 1;
        char* const pwb = (char*)&Pl[bw][0];
#pragma unroll
        for (int s4 = 0; s4 < 4; ++s4) {
            uint2 pk;
            pk.x = pkbf(e[s4][0], e[s4][1]);
            pk.y = pkbf(e[s4][2], e[s4][3]);
            *(uint2*)(pwb + myrow + (((unsigned)(s4 * 32 + g * 8)) ^ swz)) = pk;
        }
        if (g == 0) scb[bw][w * 16 + ln] = sc;
        const int allsk = __all(sc == 1.0f);
        if (lane == 0) flg[bw][w] = allsk;

        // ---- barrier: drain K(t+1) DMA + V(t+1... issued in prev PV) + ds
        asm volatile("s_waitcnt vmcnt(0) lgkmcnt(0)" ::: "memory");
        __builtin_amdgcn_s_barrier();

        // ---- V(t+1) DMA (all waves, 2 each); WAR-safe: Vl[nbuf] readers
        // finished before this barrier; drains at next iter's barrier.
#pragma unroll
        for (int i = 0; i < 2; ++i) {
            const unsigned short* vsrc = vBb + (size_t)(w * 16 + i * 8 + (lane >> 3)) * NPX + mnext + vko;
            __builtin_amdgcn_global_load_lds(
                (const __attribute__((address_space(1))) void*)vsrc,
                (__attribute__((address_space(3))) void*)&Vl[nbuf][(w * 16 + i * 8) * 64], 16, 0, 0);
        }

        // ---- rescale (skipped when all sc==1)
        int sk = flg[bw][0];
#pragma unroll
        for (int i = 1; i < NW; ++i) sk &= flg[bw][i];
        if (!sk) {
#pragma unroll
            for (int qt2 = 0; qt2 < 2; ++qt2) {
                const float scq = scb[bw][qg * 64 + qt2 * 32 + l32];
#pragma unroll
                for (int ct2 = 0; ct2 < 2; ++ct2)
#pragma unroll
                    for (int rr = 0; rr < 16; ++rr) acc2[qt2][ct2][rr] *= scq;
            }
        }

        // ---- PV: 32x32x16 MFMA, 4 kc x (2 P-frags + 2 V-frags -> 4 MFMA)
        const char* vl = (const char*)&Vl[t & 1][0];
        const char* pB = (const char*)&Pl[bw][0];
#pragma unroll
        for (int kc = 0; kc < 4; ++kc) {
            const unsigned ko = (unsigned)(kc * 32 + (h32 << 4));
            const bf16x8 pb0 = *(const bf16x8*)(pB + (qg * 64 + l32) * 128      + (ko ^ swz));
            const bf16x8 pb1 = *(const bf16x8*)(pB + (qg * 64 + 32 + l32) * 128 + (ko ^ swz));
            const bf16x8 va0 = *(const bf16x8*)(vl + (cg * 64 + l32) * 128      + (ko ^ swz));
            const bf16x8 va1 = *(const bf16x8*)(vl + (cg * 64 + 32 + l32) * 128 + (ko ^ swz));
            acc2[0][0] = __builtin_amdgcn_mfma_f32_32x32x16_bf16(va0, pb0, acc2[0][0], 0, 0, 0);
            acc2[0][1] = __builtin_amdgcn_mfma_f32_32x32x16_bf16(va1, pb0, acc2[0][1], 0, 0, 0);
            acc2[1][0] = __builtin_amdgcn_mfma_f32_32x32x16_bf16(va0, pb1, acc2[1][0], 0, 0, 0);
            acc2[1][1] = __builtin_amdgcn_mfma_f32_32x32x16_bf16(va1, pb1, acc2[1][1], 0, 0, 0);
        }
    }

    // D layout (m101): col=l32 (q), row=(rr&3)+8*(rr>>2)+4*h32 (c within tile)
    if (opart) {
        const size_t sb = (size_t)(s * NB + b);
#pragma unroll
        for (int qt2 = 0; qt2 < 2; ++qt2)
#pragma unroll
            for (int ct2 = 0; ct2 < 2; ++ct2)
#pragma unroll
                for (int rr = 0; rr < 16; ++rr) {
                    const int crow = cg * 64 + ct2 * 32 + (rr & 3) + 8 * (rr >> 2) + 4 * h32;
                    opart[(sb * CCH + crow) * NPX + n0 + qg * 64 + qt2 * 32 + l32]
                        = f2bf(acc2[qt2][ct2][rr]);
                }
        if (g == 0) {
            mlm[sb * NPX + n0 + w * 16 + ln] = mreg;   // log2 domain
            mll[sb * NPX + n0 + w * 16 + ln] = lreg;
        }
    } else {
        if (g == 0) l_lds[w * 16 + ln] = lreg;
        __syncthreads();
        const float gm = gamma[0];
#pragma unroll
        for (int qt2 = 0; qt2 < 2; ++qt2) {
            const float iv = 1.f / l_lds[qg * 64 + qt2 * 32 + l32];
#pragma unroll
            for (int ct2 = 0; ct2 < 2; ++ct2)
#pragma unroll
                for (int rr = 0; rr < 16; ++rr) {
                    const int crow = cg * 64 + ct2 * 32 + (rr & 3) + 8 * (rr >> 2) + 4 * h32;
                    const size_t idx = ((size_t)b * CCH + crow) * NPX
                                     + n0 + qg * 64 + qt2 * 32 + l32;
                    out[idx] = gm * acc2[qt2][ct2][rr] * iv + x[idx];
                }
        }
    }
}

// ---------------------------------------------------------------------------
// Combine (unchanged): merge ns partials (m in LOG2 domain) + residual.
// ---------------------------------------------------------------------------
__global__ __launch_bounds__(256) void combine_kernel(
    const unsigned short* __restrict__ opart,
    const float* __restrict__ mlm, const float* __restrict__ mll,
    const float* __restrict__ x, const float* __restrict__ gamma,
    float* __restrict__ out, int ns)
{
    const int idx = blockIdx.x * 256 + threadIdx.x;   // NB*CCH*512 threads
    const int bc  = idx >> 9;                          // b*CCH + c
    const int b   = bc / CCH;
    const int c   = bc - b * CCH;
    const int n0  = (idx & 511) * 8;

    float M[8];
#pragma unroll
    for (int i = 0; i < 8; ++i) M[i] = -INFINITY;
    for (int s = 0; s < ns; ++s) {
        const float* mp = mlm + ((size_t)(s * NB + b)) * NPX + n0;
#pragma unroll
        for (int i = 0; i < 8; ++i) M[i] = fmaxf(M[i], mp[i]);
    }

    float L[8], O[8];
#pragma unroll
    for (int i = 0; i < 8; ++i) { L[i] = 0.f; O[i] = 0.f; }
    for (int s = 0; s < ns; ++s) {
        const size_t sb = (size_t)(s * NB + b);
        const float* mp = mlm + sb * NPX + n0;
        const float* lp = mll + sb * NPX + n0;
        const bf16x8 v8 = *(const bf16x8*)(opart + (sb * CCH + c) * NPX + n0);
#pragma unroll
        for (int i = 0; i < 8; ++i) {
            const float wgt = EXP2F(mp[i] - M[i]);   // log2-domain merge
            L[i] += wgt * lp[i];
            O[i] += wgt * bf2f((unsigned short)v8[i]);
        }
    }

    const float gm = gamma[0];
    const size_t xo = (size_t)bc * NPX + n0;
    float4 r0, r1;
    const float4 x0 = *(const float4*)(x + xo);
    const float4 x1 = *(const float4*)(x + xo + 4);
    r0.x = gm * O[0] / L[0] + x0.x;  r0.y = gm * O[1] / L[1] + x0.y;
    r0.z = gm * O[2] / L[2] + x0.z;  r0.w = gm * O[3] / L[3] + x0.w;
    r1.x = gm * O[4] / L[4] + x1.x;  r1.y = gm * O[5] / L[5] + x1.y;
    r1.z = gm * O[6] / L[6] + x1.z;  r1.w = gm * O[7] / L[7] + x1.w;
    *(float4*)(out + xo)     = r0;
    *(float4*)(out + xo + 4) = r1;
}

extern "C" void kernel_launch(void* const* d_in, const int* in_sizes, int n_in,
                              void* d_out, int out_size, void* d_ws, size_t ws_size,
                              hipStream_t stream)
{
    const float* x  = (const float*)d_in[0];
    const float* Wq = (const float*)d_in[1];
    const float* bq = (const float*)d_in[2];
    const float* Wk = (const float*)d_in[3];
    const float* bk = (const float*)d_in[4];
    const float* Wv = (const float*)d_in[5];
    const float* bv = (const float*)d_in[6];
    const float* gm = (const float*)d_in[7];
    float* out = (float*)d_out;
    unsigned short* ws = (unsigned short*)d_ws;

    const size_t WB_U16 = 320 * CCH;          // 81920
    const size_t BB_U16 = 320 * 2;            // 320 floats
    const size_t qkvU   = (size_t)2 * NB * NPX * 32 + (size_t)NB * CCH * NPX;
    const size_t qkvB   = (qkvU + WB_U16 + BB_U16) * 2;
    const size_t partB  = (size_t)NB * CCH * NPX * 2;                        // 8 MB / slice
    const size_t mlB    = (size_t)2 * NB * NPX * 4;                          // 128 KB / slice
    int ns = 1;
    if      (ws_size >= qkvB + 4 * (partB + mlB)) ns = 4;
    else if (ws_size >= qkvB + 2 * (partB + mlB)) ns = 2;

    unsigned short* Wb = ws + qkvU;
    float*          bb = (float*)(ws + qkvU + WB_U16);

    convert_kernel<<<320, 256, 0, stream>>>(Wq, bq, Wk, bk, Wv, bv, Wb, bb);

    // proj: 8 XCD x (32 slabs x 5 ocg) = 1280 blocks, 512 thr
    proj_mfma<<<1280, 512, 0, stream>>>(x, Wb, bb, ws);

    const unsigned short* qT = ws;
    const unsigned short* kT = ws + (size_t)NB * NPX * 32;
    const unsigned short* vB = ws + (size_t)2 * NB * NPX * 32;

    // attn: NB x (NPX/BQK) tiles x ns slices, 1024 thr (16 waves)
    const int ablocks = NB * (NPX / BQK) * ns;

    if (ns > 1) {
        unsigned short* opart = ws + qkvU + WB_U16 + BB_U16;
        float* mlm = (float*)(opart + (size_t)ns * NB * CCH * NPX);
        float* mll = mlm + (size_t)ns * NB * NPX;

        attn_kernel<<<ablocks, 1024, 0, stream>>>(qT, kT, vB, x, gm, out,
                                                  opart, mlm, mll, ns);

        const int cblocks = (NB * CCH * (NPX / 8)) / 256;
        combine_kernel<<<cblocks, 256, 0, stream>>>(opart, mlm, mll, x, gm, out, ns);
    } else {
        attn_kernel<<<ablocks, 1024, 0, stream>>>(qT, kT, vB, x, gm, out,
                                                  nullptr, nullptr, nullptr, 1);
    }
}

// Round 22
// 91.029 us; speedup vs baseline: 1.0464x; 1.0464x over previous
//
#include <hip/hip_runtime.h>
#include <hip/hip_bf16.h>
#include <cstddef>
#include <cstdint>

#define CCH 256   // channels
#define DQK 32    // q/k channels
#define NPX 4096  // H*W
#define BQ2 128   // queries per block (8 waves x 16-query strips)
#define BM  64    // key tile per iteration
#define NB  4     // batch

typedef __attribute__((ext_vector_type(8))) short bf16x8;   // 8 bf16 = 4 VGPR (MFMA A/B frag)
typedef __attribute__((ext_vector_type(4))) float f32x4;    // MFMA C/D frag
typedef __attribute__((ext_vector_type(4))) unsigned int u32x4;

#if __has_builtin(__builtin_amdgcn_exp2f)
#define EXP2F(x) __builtin_amdgcn_exp2f(x)
#else
#define EXP2F(x) exp2f(x)
#endif

__device__ inline unsigned short f2bf(float f) {            // RNE float->bf16
    unsigned u = __builtin_bit_cast(unsigned, f);
    u += 0x7FFFu + ((u >> 16) & 1u);
    return (unsigned short)(u >> 16);
}
__device__ inline float bf2f(unsigned short h) {
    unsigned u = (unsigned)h << 16;
    return __builtin_bit_cast(float, u);
}
__device__ inline unsigned pkbf(float a, float b) {         // v_cvt_pk_bf16_f32
    __hip_bfloat162 h = __float22bfloat162_rn(make_float2(a, b));
    unsigned u;
    __builtin_memcpy(&u, &h, 4);                            // a in low 16 bits
    return u;
}

// ---------------------------------------------------------------------------
// convert_kernel: W -> bf16, Wq/bq scaled by log2(e) (exp2-domain softmax).
// ---------------------------------------------------------------------------
__global__ __launch_bounds__(256) void convert_kernel(
    const float* __restrict__ Wq, const float* __restrict__ bq,
    const float* __restrict__ Wk, const float* __restrict__ bk,
    const float* __restrict__ Wv, const float* __restrict__ bv,
    unsigned short* __restrict__ Wb, float* __restrict__ bb)
{
    const float LOG2E = 1.4426950408889634f;
    const int o = blockIdx.x;
    const int c = threadIdx.x;
    float v;
    if (o < 32)       v = Wq[o * CCH + c] * LOG2E;
    else if (o < 64)  v = Wk[(o - 32) * CCH + c];
    else              v = Wv[(o - 64) * CCH + c];
    Wb[o * CCH + c] = f2bf(v);
    if (c == 0)
        bb[o] = (o < 32) ? bq[o] * LOG2E : (o < 64) ? bk[o - 32] : bv[o - 64];
}

// ---------------------------------------------------------------------------
// proj_mfma (verified R14): out[oc][px] = sum_c W[oc][c] x[c][px] + bias.
// ---------------------------------------------------------------------------
__global__ __launch_bounds__(512) void proj_mfma(
    const float* __restrict__ x,
    const unsigned short* __restrict__ Wb, const float* __restrict__ bb,
    unsigned short* __restrict__ ws)
{
    __shared__ __align__(16) unsigned short xT[64][264];   // 33 KB

    const int tid  = threadIdx.x;
    const int lane = tid & 63;
    const int w    = tid >> 6;
    const int ln   = lane & 15;
    const int g    = lane >> 4;
    const int bid  = blockIdx.x;

    const int xcd  = bid & 7;
    const int idx  = bid >> 3;             // 0..159
    const int slab = xcd + 8 * (idx / 5);  // 0..255
    const int ocg  = idx % 5;
    const int b    = slab >> 6;
    const int pxt  = slab & 63;
    const int pxg0 = pxt * 64;

    const int mt    = w >> 1;
    const int ocrow = ocg * 64 + mt * 16 + ln;
    bf16x8 a[8];
#pragma unroll
    for (int k8 = 0; k8 < 8; ++k8)
        a[k8] = *(const bf16x8*)(Wb + (size_t)ocrow * CCH + k8 * 32 + g * 8);

    {
        const int pxl = (tid & 15) * 4;
        const int c0  = (tid >> 4) * 8;
        float4 xv[8];
#pragma unroll
        for (int cc = 0; cc < 8; ++cc)
            xv[cc] = *(const float4*)(x + ((size_t)(b * CCH + c0 + cc)) * NPX + pxg0 + pxl);
#pragma unroll
        for (int j = 0; j < 4; ++j) {
            unsigned u[4];
#pragma unroll
            for (int h = 0; h < 4; ++h) {
                const float f0 = ((const float*)&xv[2 * h])[j];
                const float f1 = ((const float*)&xv[2 * h + 1])[j];
                u[h] = pkbf(f0, f1);
            }
            *(u32x4*)&xT[pxl + j][c0] = (u32x4){u[0], u[1], u[2], u[3]};
        }
    }
    __syncthreads();

    const int nt0 = (w & 1) * 2;
    const float4 bb4 = *(const float4*)(bb + ocg * 64 + mt * 16 + g * 4);
    f32x4 acc0 = (f32x4){bb4.x, bb4.y, bb4.z, bb4.w};
    f32x4 acc1 = acc0;
#pragma unroll
    for (int k8 = 0; k8 < 8; ++k8) {
        const bf16x8 b0 = *(const bf16x8*)&xT[nt0 * 16 + ln][k8 * 32 + g * 8];
        const bf16x8 b1 = *(const bf16x8*)&xT[nt0 * 16 + 16 + ln][k8 * 32 + g * 8];
        acc0 = __builtin_amdgcn_mfma_f32_16x16x32_bf16(a[k8], b0, acc0, 0, 0, 0);
        acc1 = __builtin_amdgcn_mfma_f32_16x16x32_bf16(a[k8], b1, acc1, 0, 0, 0);
    }

    unsigned short* qT = ws;
    unsigned short* kT = ws + (size_t)NB * NPX * 32;
    unsigned short* vb = ws + (size_t)2 * NB * NPX * 32;
#pragma unroll
    for (int j = 0; j < 2; ++j) {
        const f32x4 acc = j ? acc1 : acc0;
        const int px = pxg0 + (nt0 + j) * 16 + ln;
        if (ocg == 0) {
            const unsigned lo = pkbf(acc[0], acc[1]);
            const unsigned hi = pkbf(acc[2], acc[3]);
            unsigned short* dst = (mt < 2)
                ? qT + ((size_t)b * NPX + px) * 32 + mt * 16 + g * 4
                : kT + ((size_t)b * NPX + px) * 32 + (mt - 2) * 16 + g * 4;
            *(uint2*)dst = make_uint2(lo, hi);
        } else {
            const int c_row = (ocg - 1) * 64 + mt * 16 + g * 4;
#pragma unroll
            for (int rr = 0; rr < 4; ++rr)
                vb[((size_t)(b * CCH + c_row + rr)) * NPX + px] = f2bf(acc[rr]);
        }
    }
}

// ---------------------------------------------------------------------------
// Flash attention (R18 exact — session best: 61.3us attn, 92.3us total).
// 8 waves/512thr, raw lgkm-only barrier, pre-barrier V loads, exp2 softmax
// (log2e folded into q at proj), defer-max, pkbf P pack, ns=4 key slices.
// ---------------------------------------------------------------------------
__global__ __launch_bounds__(512, 4) void attn_kernel(
    const unsigned short* __restrict__ qT, const unsigned short* __restrict__ kT,
    const unsigned short* __restrict__ vB, const float* __restrict__ x,
    const float* __restrict__ gamma, float* __restrict__ out,
    unsigned short* __restrict__ opart, float* __restrict__ mlm,
    float* __restrict__ mll, int ns)
{
    __shared__ __align__(16) unsigned short Pl[2][BQ2 * 64];  // 32KB, XOR swz
    __shared__ float scb[2][BQ2];
    __shared__ int   flg[2][8];
    __shared__ float l_lds[BQ2];

    const int tid  = threadIdx.x;
    const int lane = tid & 63;
    const int w    = tid >> 6;       // wave 0..7
    const int ln   = lane & 15;
    const int g    = lane >> 4;      // 16-lane group 0..3
    const int bid  = blockIdx.x;

    const int b    = (bid & 7) >> 1;                        // batch -> XCD pair
    const int jb   = ((bid >> 3) << 1) | (bid & 1);         // job in batch
    const int tile = jb / ns;
    const int s    = jb - tile * ns;
    const int n0   = tile * BQ2;

    const bf16x8 qf = *(const bf16x8*)(qT + ((size_t)b * NPX + n0 + w * 16 + ln) * 32 + g * 8);

    f32x4 acc[8][2];
#pragma unroll
    for (int qt = 0; qt < 8; ++qt) {
        acc[qt][0] = (f32x4){0.f, 0.f, 0.f, 0.f};
        acc[qt][1] = (f32x4){0.f, 0.f, 0.f, 0.f};
    }
    float mreg = -INFINITY, lreg = 0.f;

    const unsigned short* kTb = kT + (size_t)b * NPX * 32;
    const unsigned short* vb  = vB + ((size_t)b * CCH + w * 32) * NPX;
    const int kbase = s * (NPX / ns);
    const int iters = NPX / (ns * BM);
    const unsigned swz   = ((unsigned)ln & 7u) << 4;
    const unsigned myrow = (unsigned)(w * 16 + ln) * 128u;
    const float THR2 = 11.544655f;   // 8 * log2(e): P bounded by e^8

    for (int t = 0; t < iters; ++t) {
        const int m0 = kbase + t * BM;

        f32x4 e[4];
#pragma unroll
        for (int s4 = 0; s4 < 4; ++s4) {
            const bf16x8 ka = *(const bf16x8*)(kTb + (size_t)(m0 + s4 * 16 + ln) * 32 + g * 8);
            e[s4] = __builtin_amdgcn_mfma_f32_16x16x32_bf16(
                        ka, qf, (f32x4){0.f, 0.f, 0.f, 0.f}, 0, 0, 0);
        }

        float lm = -INFINITY;
#pragma unroll
        for (int s4 = 0; s4 < 4; ++s4)
#pragma unroll
            for (int rr = 0; rr < 4; ++rr) lm = fmaxf(lm, e[s4][rr]);
        lm = fmaxf(lm, __shfl_xor(lm, 16));
        lm = fmaxf(lm, __shfl_xor(lm, 32));
        const float mnew = (lm <= mreg + THR2) ? mreg : lm;  // -inf -> first iter updates
        const float sc   = EXP2F(mreg - mnew);               // ==1.0 exactly when deferred
        float ps = 0.f;
#pragma unroll
        for (int s4 = 0; s4 < 4; ++s4)
#pragma unroll
            for (int rr = 0; rr < 4; ++rr) {
                const float p = EXP2F(e[s4][rr] - mnew);
                e[s4][rr] = p;
                ps += p;
            }
        ps += __shfl_xor(ps, 16);
        ps += __shfl_xor(ps, 32);
        lreg = lreg * sc + ps;
        mreg = mnew;

        const int bw = t & 1;
        char* const pwb = (char*)&Pl[bw][0];
#pragma unroll
        for (int s4 = 0; s4 < 4; ++s4) {
            uint2 pk;
            pk.x = pkbf(e[s4][0], e[s4][1]);
            pk.y = pkbf(e[s4][2], e[s4][3]);
            *(uint2*)(pwb + myrow + (((unsigned)(s4 * 32 + g * 8)) ^ swz)) = pk;
        }
        if (g == 0) scb[bw][w * 16 + ln] = sc;
        const int allsk = __all(sc == 1.0f);
        if (lane == 0) flg[bw][w] = allsk;

        // V(t) loads PRE-barrier; stay in flight across the raw barrier.
        bf16x8 va[2][2];
#pragma unroll
        for (int ct = 0; ct < 2; ++ct) {
            const unsigned short* vrow = vb + (size_t)(ct * 16 + ln) * NPX + m0 + g * 8;
            va[ct][0] = *(const bf16x8*)(vrow);
            va[ct][1] = *(const bf16x8*)(vrow + 32);
        }

        // raw barrier: drain ONLY lgkm (ds_writes of P/scb/flg).
        asm volatile("s_waitcnt lgkmcnt(0)" ::: "memory");
        __builtin_amdgcn_s_barrier();

        int sk = flg[bw][0];
#pragma unroll
        for (int i = 1; i < 8; ++i) sk &= flg[bw][i];
        if (!sk) {
#pragma unroll
            for (int qt = 0; qt < 8; ++qt) {
                const float scq = scb[bw][qt * 16 + ln];
#pragma unroll
                for (int rr = 0; rr < 4; ++rr) {
                    acc[qt][0][rr] *= scq;
                    acc[qt][1][rr] *= scq;
                }
            }
        }
#pragma unroll
        for (int qt = 0; qt < 8; ++qt) {
            const unsigned rb = (unsigned)(qt * 16 + ln) * 128u;
            const bf16x8 pf0 = *(const bf16x8*)(pwb + rb + (((unsigned)(g * 16))      ^ swz));
            const bf16x8 pf1 = *(const bf16x8*)(pwb + rb + (((unsigned)(64 + g * 16)) ^ swz));
            acc[qt][0] = __builtin_amdgcn_mfma_f32_16x16x32_bf16(va[0][0], pf0, acc[qt][0], 0, 0, 0);
            acc[qt][0] = __builtin_amdgcn_mfma_f32_16x16x32_bf16(va[0][1], pf1, acc[qt][0], 0, 0, 0);
            acc[qt][1] = __builtin_amdgcn_mfma_f32_16x16x32_bf16(va[1][0], pf0, acc[qt][1], 0, 0, 0);
            acc[qt][1] = __builtin_amdgcn_mfma_f32_16x16x32_bf16(va[1][1], pf1, acc[qt][1], 0, 0, 0);
        }
    }

    if (opart) {
        const size_t sb = (size_t)(s * NB + b);
#pragma unroll
        for (int qt = 0; qt < 8; ++qt)
#pragma unroll
            for (int ct = 0; ct < 2; ++ct) {
                const size_t c0 = sb * CCH + w * 32 + ct * 16 + g * 4;
#pragma unroll
                for (int rr = 0; rr < 4; ++rr)
                    opart[(c0 + rr) * NPX + n0 + qt * 16 + ln] = f2bf(acc[qt][ct][rr]);
            }
        if (g == 0) {
            mlm[sb * NPX + n0 + w * 16 + ln] = mreg;   // log2 domain
            mll[sb * NPX + n0 + w * 16 + ln] = lreg;
        }
    } else {
        if (g == 0) l_lds[w * 16 + ln] = lreg;
        __syncthreads();
        const float gm = gamma[0];
#pragma unroll
        for (int qt = 0; qt < 8; ++qt) {
            const float iv = 1.f / l_lds[qt * 16 + ln];
#pragma unroll
            for (int ct = 0; ct < 2; ++ct) {
                const size_t c0 = (size_t)b * CCH + w * 32 + ct * 16 + g * 4;
#pragma unroll
                for (int rr = 0; rr < 4; ++rr) {
                    const size_t idx = (c0 + rr) * NPX + n0 + qt * 16 + ln;
                    out[idx] = gm * acc[qt][ct][rr] * iv + x[idx];
                }
            }
        }
    }
}

// ---------------------------------------------------------------------------
// Combine: merge of ns key-slice partials (m in LOG2 domain) + residual.
// ---------------------------------------------------------------------------
__global__ __launch_bounds__(256) void combine_kernel(
    const unsigned short* __restrict__ opart,
    const float* __restrict__ mlm, const float* __restrict__ mll,
    const float* __restrict__ x, const float* __restrict__ gamma,
    float* __restrict__ out, int ns)
{
    const int idx = blockIdx.x * 256 + threadIdx.x;   // NB*CCH*512 threads
    const int bc  = idx >> 9;                          // b*CCH + c
    const int b   = bc / CCH;
    const int c   = bc - b * CCH;
    const int n0  = (idx & 511) * 8;

    float M[8];
#pragma unroll
    for (int i = 0; i < 8; ++i) M[i] = -INFINITY;
    for (int s = 0; s < ns; ++s) {
        const float* mp = mlm + ((size_t)(s * NB + b)) * NPX + n0;
#pragma unroll
        for (int i = 0; i < 8; ++i) M[i] = fmaxf(M[i], mp[i]);
    }

    float L[8], O[8];
#pragma unroll
    for (int i = 0; i < 8; ++i) { L[i] = 0.f; O[i] = 0.f; }
    for (int s = 0; s < ns; ++s) {
        const size_t sb = (size_t)(s * NB + b);
        const float* mp = mlm + sb * NPX + n0;
        const float* lp = mll + sb * NPX + n0;
        const bf16x8 v8 = *(const bf16x8*)(opart + (sb * CCH + c) * NPX + n0);
#pragma unroll
        for (int i = 0; i < 8; ++i) {
            const float wgt = EXP2F(mp[i] - M[i]);   // log2-domain merge
            L[i] += wgt * lp[i];
            O[i] += wgt * bf2f((unsigned short)v8[i]);
        }
    }

    const float gm = gamma[0];
    const size_t xo = (size_t)bc * NPX + n0;
    float4 r0, r1;
    const float4 x0 = *(const float4*)(x + xo);
    const float4 x1 = *(const float4*)(x + xo + 4);
    r0.x = gm * O[0] / L[0] + x0.x;  r0.y = gm * O[1] / L[1] + x0.y;
    r0.z = gm * O[2] / L[2] + x0.z;  r0.w = gm * O[3] / L[3] + x0.w;
    r1.x = gm * O[4] / L[4] + x1.x;  r1.y = gm * O[5] / L[5] + x1.y;
    r1.z = gm * O[6] / L[6] + x1.z;  r1.w = gm * O[7] / L[7] + x1.w;
    *(float4*)(out + xo)     = r0;
    *(float4*)(out + xo + 4) = r1;
}

extern "C" void kernel_launch(void* const* d_in, const int* in_sizes, int n_in,
                              void* d_out, int out_size, void* d_ws, size_t ws_size,
                              hipStream_t stream)
{
    const float* x  = (const float*)d_in[0];
    const float* Wq = (const float*)d_in[1];
    const float* bq = (const float*)d_in[2];
    const float* Wk = (const float*)d_in[3];
    const float* bk = (const float*)d_in[4];
    const float* Wv = (const float*)d_in[5];
    const float* bv = (const float*)d_in[6];
    const float* gm = (const float*)d_in[7];
    float* out = (float*)d_out;
    unsigned short* ws = (unsigned short*)d_ws;

    const size_t WB_U16 = 320 * CCH;          // 81920
    const size_t BB_U16 = 320 * 2;            // 320 floats
    const size_t qkvU   = (size_t)2 * NB * NPX * 32 + (size_t)NB * CCH * NPX;
    const size_t qkvB   = (qkvU + WB_U16 + BB_U16) * 2;
    const size_t partB  = (size_t)NB * CCH * NPX * 2;                        // 8 MB / slice
    const size_t mlB    = (size_t)2 * NB * NPX * 4;                          // 128 KB / slice
    int ns = 1;
    if      (ws_size >= qkvB + 4 * (partB + mlB)) ns = 4;
    else if (ws_size >= qkvB + 2 * (partB + mlB)) ns = 2;

    unsigned short* Wb = ws + qkvU;
    float*          bb = (float*)(ws + qkvU + WB_U16);

    convert_kernel<<<320, 256, 0, stream>>>(Wq, bq, Wk, bk, Wv, bv, Wb, bb);

    // proj: 8 XCD x (32 slabs x 5 ocg) = 1280 blocks, 512 thr
    proj_mfma<<<1280, 512, 0, stream>>>(x, Wb, bb, ws);

    const unsigned short* qT = ws;
    const unsigned short* kT = ws + (size_t)NB * NPX * 32;
    const unsigned short* vB = ws + (size_t)2 * NB * NPX * 32;

    const int ablocks = NB * (NPX / BQ2) * ns;

    if (ns > 1) {
        unsigned short* opart = ws + qkvU + WB_U16 + BB_U16;
        float* mlm = (float*)(opart + (size_t)ns * NB * CCH * NPX);
        float* mll = mlm + (size_t)ns * NB * NPX;

        attn_kernel<<<ablocks, 512, 0, stream>>>(qT, kT, vB, x, gm, out,
                                                 opart, mlm, mll, ns);

        const int cblocks = (NB * CCH * (NPX / 8)) / 256;
        combine_kernel<<<cblocks, 256, 0, stream>>>(opart, mlm, mll, x, gm, out, ns);
    } else {
        attn_kernel<<<ablocks, 512, 0, stream>>>(qT, kT, vB, x, gm, out,
                                                 nullptr, nullptr, nullptr, 1);
    }
}

// Round 23
// 87.068 us; speedup vs baseline: 1.0940x; 1.0455x over previous
//
#include <hip/hip_runtime.h>
#include <hip/hip_bf16.h>
#include <cstddef>
#include <cstdint>

#define CCH 256   // channels
#define DQK 32    // q/k channels
#define NPX 4096  // H*W
#define BQ2 128   // queries per block (8 waves x 16-query strips)
#define BM  64    // key tile per iteration
#define NB  4     // batch

typedef __attribute__((ext_vector_type(8))) short bf16x8;   // 8 bf16 = 4 VGPR (MFMA A/B frag)
typedef __attribute__((ext_vector_type(4))) float f32x4;    // MFMA C/D frag
typedef __attribute__((ext_vector_type(4))) unsigned int u32x4;

#if __has_builtin(__builtin_amdgcn_exp2f)
#define EXP2F(x) __builtin_amdgcn_exp2f(x)
#else
#define EXP2F(x) exp2f(x)
#endif

__device__ inline unsigned short f2bf(float f) {            // RNE float->bf16
    unsigned u = __builtin_bit_cast(unsigned, f);
    u += 0x7FFFu + ((u >> 16) & 1u);
    return (unsigned short)(u >> 16);
}
__device__ inline float bf2f(unsigned short h) {
    unsigned u = (unsigned)h << 16;
    return __builtin_bit_cast(float, u);
}
__device__ inline unsigned pkbf(float a, float b) {         // v_cvt_pk_bf16_f32
    __hip_bfloat162 h = __float22bfloat162_rn(make_float2(a, b));
    unsigned u;
    __builtin_memcpy(&u, &h, 4);                            // a in low 16 bits
    return u;
}

// ---------------------------------------------------------------------------
// convert_kernel: W -> bf16, Wq/bq scaled by log2(e) (exp2-domain softmax).
// ---------------------------------------------------------------------------
__global__ __launch_bounds__(256) void convert_kernel(
    const float* __restrict__ Wq, const float* __restrict__ bq,
    const float* __restrict__ Wk, const float* __restrict__ bk,
    const float* __restrict__ Wv, const float* __restrict__ bv,
    unsigned short* __restrict__ Wb, float* __restrict__ bb)
{
    const float LOG2E = 1.4426950408889634f;
    const int o = blockIdx.x;
    const int c = threadIdx.x;
    float v;
    if (o < 32)       v = Wq[o * CCH + c] * LOG2E;
    else if (o < 64)  v = Wk[(o - 32) * CCH + c];
    else              v = Wv[(o - 64) * CCH + c];
    Wb[o * CCH + c] = f2bf(v);
    if (c == 0)
        bb[o] = (o < 32) ? bq[o] * LOG2E : (o < 64) ? bk[o - 32] : bv[o - 64];
}

// ---------------------------------------------------------------------------
// proj_mfma (verified R14): out[oc][px] = sum_c W[oc][c] x[c][px] + bias.
// ---------------------------------------------------------------------------
__global__ __launch_bounds__(512) void proj_mfma(
    const float* __restrict__ x,
    const unsigned short* __restrict__ Wb, const float* __restrict__ bb,
    unsigned short* __restrict__ ws)
{
    __shared__ __align__(16) unsigned short xT[64][264];   // 33 KB

    const int tid  = threadIdx.x;
    const int lane = tid & 63;
    const int w    = tid >> 6;
    const int ln   = lane & 15;
    const int g    = lane >> 4;
    const int bid  = blockIdx.x;

    const int xcd  = bid & 7;
    const int idx  = bid >> 3;             // 0..159
    const int slab = xcd + 8 * (idx / 5);  // 0..255
    const int ocg  = idx % 5;
    const int b    = slab >> 6;
    const int pxt  = slab & 63;
    const int pxg0 = pxt * 64;

    const int mt    = w >> 1;
    const int ocrow = ocg * 64 + mt * 16 + ln;
    bf16x8 a[8];
#pragma unroll
    for (int k8 = 0; k8 < 8; ++k8)
        a[k8] = *(const bf16x8*)(Wb + (size_t)ocrow * CCH + k8 * 32 + g * 8);

    {
        const int pxl = (tid & 15) * 4;
        const int c0  = (tid >> 4) * 8;
        float4 xv[8];
#pragma unroll
        for (int cc = 0; cc < 8; ++cc)
            xv[cc] = *(const float4*)(x + ((size_t)(b * CCH + c0 + cc)) * NPX + pxg0 + pxl);
#pragma unroll
        for (int j = 0; j < 4; ++j) {
            unsigned u[4];
#pragma unroll
            for (int h = 0; h < 4; ++h) {
                const float f0 = ((const float*)&xv[2 * h])[j];
                const float f1 = ((const float*)&xv[2 * h + 1])[j];
                u[h] = pkbf(f0, f1);
            }
            *(u32x4*)&xT[pxl + j][c0] = (u32x4){u[0], u[1], u[2], u[3]};
        }
    }
    __syncthreads();

    const int nt0 = (w & 1) * 2;
    const float4 bb4 = *(const float4*)(bb + ocg * 64 + mt * 16 + g * 4);
    f32x4 acc0 = (f32x4){bb4.x, bb4.y, bb4.z, bb4.w};
    f32x4 acc1 = acc0;
#pragma unroll
    for (int k8 = 0; k8 < 8; ++k8) {
        const bf16x8 b0 = *(const bf16x8*)&xT[nt0 * 16 + ln][k8 * 32 + g * 8];
        const bf16x8 b1 = *(const bf16x8*)&xT[nt0 * 16 + 16 + ln][k8 * 32 + g * 8];
        acc0 = __builtin_amdgcn_mfma_f32_16x16x32_bf16(a[k8], b0, acc0, 0, 0, 0);
        acc1 = __builtin_amdgcn_mfma_f32_16x16x32_bf16(a[k8], b1, acc1, 0, 0, 0);
    }

    unsigned short* qT = ws;
    unsigned short* kT = ws + (size_t)NB * NPX * 32;
    unsigned short* vb = ws + (size_t)2 * NB * NPX * 32;
#pragma unroll
    for (int j = 0; j < 2; ++j) {
        const f32x4 acc = j ? acc1 : acc0;
        const int px = pxg0 + (nt0 + j) * 16 + ln;
        if (ocg == 0) {
            const unsigned lo = pkbf(acc[0], acc[1]);
            const unsigned hi = pkbf(acc[2], acc[3]);
            unsigned short* dst = (mt < 2)
                ? qT + ((size_t)b * NPX + px) * 32 + mt * 16 + g * 4
                : kT + ((size_t)b * NPX + px) * 32 + (mt - 2) * 16 + g * 4;
            *(uint2*)dst = make_uint2(lo, hi);
        } else {
            const int c_row = (ocg - 1) * 64 + mt * 16 + g * 4;
#pragma unroll
            for (int rr = 0; rr < 4; ++rr)
                vb[((size_t)(b * CCH + c_row + rr)) * NPX + px] = f2bf(acc[rr]);
        }
    }
}

// ---------------------------------------------------------------------------
// Flash attention R23 = R18 + ISOLATED K-LDS double-buffer:
// waves 0-3 DMA K(t+1) (1KB each) via global_load_lds at top of iter,
// order-pinned oldest (sched_barrier); gate = vmcnt(4) so the 4 pre-barrier
// V loads stay in flight. K tile XOR-swizzled both sides (src pre-swizzle +
// read swizzle, same involution) to kill the [64][32] 8-way bank conflict.
// Everything else identical to R18 (session-best 61.3us).
// ---------------------------------------------------------------------------
__global__ __launch_bounds__(512, 4) void attn_kernel(
    const unsigned short* __restrict__ qT, const unsigned short* __restrict__ kT,
    const unsigned short* __restrict__ vB, const float* __restrict__ x,
    const float* __restrict__ gamma, float* __restrict__ out,
    unsigned short* __restrict__ opart, float* __restrict__ mlm,
    float* __restrict__ mll, int ns)
{
    __shared__ __align__(16) unsigned short Pl[2][BQ2 * 64];  // 32KB, XOR swz
    __shared__ __align__(16) unsigned short Kl[2][64 * 32];   // 8KB K stage
    __shared__ float scb[2][BQ2];
    __shared__ int   flg[2][8];
    __shared__ float l_lds[BQ2];

    const int tid  = threadIdx.x;
    const int lane = tid & 63;
    const int w    = tid >> 6;       // wave 0..7
    const int ln   = lane & 15;
    const int g    = lane >> 4;      // 16-lane group 0..3
    const int bid  = blockIdx.x;

    const int b    = (bid & 7) >> 1;                        // batch -> XCD pair
    const int jb   = ((bid >> 3) << 1) | (bid & 1);         // job in batch
    const int tile = jb / ns;
    const int s    = jb - tile * ns;
    const int n0   = tile * BQ2;

    const bf16x8 qf = *(const bf16x8*)(qT + ((size_t)b * NPX + n0 + w * 16 + ln) * 32 + g * 8);

    f32x4 acc[8][2];
#pragma unroll
    for (int qt = 0; qt < 8; ++qt) {
        acc[qt][0] = (f32x4){0.f, 0.f, 0.f, 0.f};
        acc[qt][1] = (f32x4){0.f, 0.f, 0.f, 0.f};
    }
    float mreg = -INFINITY, lreg = 0.f;

    const unsigned short* kTb = kT + (size_t)b * NPX * 32;
    const unsigned short* vb  = vB + ((size_t)b * CCH + w * 32) * NPX;
    const int kbase = s * (NPX / ns);
    const int iters = NPX / (ns * BM);
    const unsigned swz   = ((unsigned)ln & 7u) << 4;
    const unsigned myrow = (unsigned)(w * 16 + ln) * 128u;
    const float THR2 = 11.544655f;   // 8 * log2(e): P bounded by e^8

    // K DMA source pre-swizzle (involution of the read-side swizzle):
    // dst byte (linear) = w*1024 + lane*16; swz bits = ((lane>>3)&3)<<4
    const unsigned kdst  = (unsigned)w * 1024u + (unsigned)lane * 16u;
    const unsigned ksoff = (kdst ^ ((((unsigned)lane >> 3) & 3u) << 4)) >> 1;  // ushorts

    // ---- prologue: stage K(0) into Kl[0]
    if (w < 4) {
        const unsigned short* ksrc = kTb + (size_t)kbase * 32 + ksoff;
        __builtin_amdgcn_global_load_lds(
            (const __attribute__((address_space(1))) void*)ksrc,
            (__attribute__((address_space(3))) void*)&Kl[0][w * 512], 16, 0, 0);
    }
    asm volatile("s_waitcnt vmcnt(0)" ::: "memory");
    __syncthreads();

    for (int t = 0; t < iters; ++t) {
        const int m0 = kbase + t * BM;
        const int mnext = (t + 1 < iters) ? (m0 + BM) : m0;

        // ---- K(t+1) DMA first (waves 0-3), pinned oldest in VMEM order
        if (w < 4) {
            const unsigned short* ksrc = kTb + (size_t)mnext * 32 + ksoff;
            __builtin_amdgcn_global_load_lds(
                (const __attribute__((address_space(1))) void*)ksrc,
                (__attribute__((address_space(3))) void*)&Kl[(t + 1) & 1][w * 512], 16, 0, 0);
        }
        __builtin_amdgcn_sched_barrier(0);   // keep DMA oldest vs V loads

        // ---- E from LDS-staged K (read-side XOR swizzle: ((m>>1)&3)<<4)
        const char* kl = (const char*)&Kl[t & 1][0];
        f32x4 e[4];
#pragma unroll
        for (int s4 = 0; s4 < 4; ++s4) {
            const unsigned kb = (unsigned)(s4 * 16 + ln) * 64u + (unsigned)g * 16u;
            const bf16x8 ka = *(const bf16x8*)(kl + (kb ^ ((((unsigned)ln >> 1) & 3u) << 4)));
            e[s4] = __builtin_amdgcn_mfma_f32_16x16x32_bf16(
                        ka, qf, (f32x4){0.f, 0.f, 0.f, 0.f}, 0, 0, 0);
        }

        float lm = -INFINITY;
#pragma unroll
        for (int s4 = 0; s4 < 4; ++s4)
#pragma unroll
            for (int rr = 0; rr < 4; ++rr) lm = fmaxf(lm, e[s4][rr]);
        lm = fmaxf(lm, __shfl_xor(lm, 16));
        lm = fmaxf(lm, __shfl_xor(lm, 32));
        const float mnew = (lm <= mreg + THR2) ? mreg : lm;  // -inf -> first iter updates
        const float sc   = EXP2F(mreg - mnew);               // ==1.0 exactly when deferred
        float ps = 0.f;
#pragma unroll
        for (int s4 = 0; s4 < 4; ++s4)
#pragma unroll
            for (int rr = 0; rr < 4; ++rr) {
                const float p = EXP2F(e[s4][rr] - mnew);
                e[s4][rr] = p;
                ps += p;
            }
        ps += __shfl_xor(ps, 16);
        ps += __shfl_xor(ps, 32);
        lreg = lreg * sc + ps;
        mreg = mnew;

        const int bw = t & 1;
        char* const pwb = (char*)&Pl[bw][0];
#pragma unroll
        for (int s4 = 0; s4 < 4; ++s4) {
            uint2 pk;
            pk.x = pkbf(e[s4][0], e[s4][1]);
            pk.y = pkbf(e[s4][2], e[s4][3]);
            *(uint2*)(pwb + myrow + (((unsigned)(s4 * 32 + g * 8)) ^ swz)) = pk;
        }
        if (g == 0) scb[bw][w * 16 + ln] = sc;
        const int allsk = __all(sc == 1.0f);
        if (lane == 0) flg[bw][w] = allsk;

        // V(t) loads PRE-barrier; stay in flight across the raw barrier.
        bf16x8 va[2][2];
#pragma unroll
        for (int ct = 0; ct < 2; ++ct) {
            const unsigned short* vrow = vb + (size_t)(ct * 16 + ln) * NPX + m0 + g * 8;
            va[ct][0] = *(const bf16x8*)(vrow);
            va[ct][1] = *(const bf16x8*)(vrow + 32);
        }

        // raw barrier: drain K DMA (older than the 4 V loads) + all ds ops;
        // V loads remain outstanding. vmcnt(4) is a no-op for waves 4-7.
        asm volatile("s_waitcnt vmcnt(4) lgkmcnt(0)" ::: "memory");
        __builtin_amdgcn_s_barrier();

        int sk = flg[bw][0];
#pragma unroll
        for (int i = 1; i < 8; ++i) sk &= flg[bw][i];
        if (!sk) {
#pragma unroll
            for (int qt = 0; qt < 8; ++qt) {
                const float scq = scb[bw][qt * 16 + ln];
#pragma unroll
                for (int rr = 0; rr < 4; ++rr) {
                    acc[qt][0][rr] *= scq;
                    acc[qt][1][rr] *= scq;
                }
            }
        }
#pragma unroll
        for (int qt = 0; qt < 8; ++qt) {
            const unsigned rb = (unsigned)(qt * 16 + ln) * 128u;
            const bf16x8 pf0 = *(const bf16x8*)(pwb + rb + (((unsigned)(g * 16))      ^ swz));
            const bf16x8 pf1 = *(const bf16x8*)(pwb + rb + (((unsigned)(64 + g * 16)) ^ swz));
            acc[qt][0] = __builtin_amdgcn_mfma_f32_16x16x32_bf16(va[0][0], pf0, acc[qt][0], 0, 0, 0);
            acc[qt][0] = __builtin_amdgcn_mfma_f32_16x16x32_bf16(va[0][1], pf1, acc[qt][0], 0, 0, 0);
            acc[qt][1] = __builtin_amdgcn_mfma_f32_16x16x32_bf16(va[1][0], pf0, acc[qt][1], 0, 0, 0);
            acc[qt][1] = __builtin_amdgcn_mfma_f32_16x16x32_bf16(va[1][1], pf1, acc[qt][1], 0, 0, 0);
        }
    }

    if (opart) {
        const size_t sb = (size_t)(s * NB + b);
#pragma unroll
        for (int qt = 0; qt < 8; ++qt)
#pragma unroll
            for (int ct = 0; ct < 2; ++ct) {
                const size_t c0 = sb * CCH + w * 32 + ct * 16 + g * 4;
#pragma unroll
                for (int rr = 0; rr < 4; ++rr)
                    opart[(c0 + rr) * NPX + n0 + qt * 16 + ln] = f2bf(acc[qt][ct][rr]);
            }
        if (g == 0) {
            mlm[sb * NPX + n0 + w * 16 + ln] = mreg;   // log2 domain
            mll[sb * NPX + n0 + w * 16 + ln] = lreg;
        }
    } else {
        if (g == 0) l_lds[w * 16 + ln] = lreg;
        __syncthreads();
        const float gm = gamma[0];
#pragma unroll
        for (int qt = 0; qt < 8; ++qt) {
            const float iv = 1.f / l_lds[qt * 16 + ln];
#pragma unroll
            for (int ct = 0; ct < 2; ++ct) {
                const size_t c0 = (size_t)b * CCH + w * 32 + ct * 16 + g * 4;
#pragma unroll
                for (int rr = 0; rr < 4; ++rr) {
                    const size_t idx = (c0 + rr) * NPX + n0 + qt * 16 + ln;
                    out[idx] = gm * acc[qt][ct][rr] * iv + x[idx];
                }
            }
        }
    }
}

// ---------------------------------------------------------------------------
// Combine: merge of ns key-slice partials (m in LOG2 domain) + residual.
// ---------------------------------------------------------------------------
__global__ __launch_bounds__(256) void combine_kernel(
    const unsigned short* __restrict__ opart,
    const float* __restrict__ mlm, const float* __restrict__ mll,
    const float* __restrict__ x, const float* __restrict__ gamma,
    float* __restrict__ out, int ns)
{
    const int idx = blockIdx.x * 256 + threadIdx.x;   // NB*CCH*512 threads
    const int bc  = idx >> 9;                          // b*CCH + c
    const int b   = bc / CCH;
    const int c   = bc - b * CCH;
    const int n0  = (idx & 511) * 8;

    float M[8];
#pragma unroll
    for (int i = 0; i < 8; ++i) M[i] = -INFINITY;
    for (int s = 0; s < ns; ++s) {
        const float* mp = mlm + ((size_t)(s * NB + b)) * NPX + n0;
#pragma unroll
        for (int i = 0; i < 8; ++i) M[i] = fmaxf(M[i], mp[i]);
    }

    float L[8], O[8];
#pragma unroll
    for (int i = 0; i < 8; ++i) { L[i] = 0.f; O[i] = 0.f; }
    for (int s = 0; s < ns; ++s) {
        const size_t sb = (size_t)(s * NB + b);
        const float* mp = mlm + sb * NPX + n0;
        const float* lp = mll + sb * NPX + n0;
        const bf16x8 v8 = *(const bf16x8*)(opart + (sb * CCH + c) * NPX + n0);
#pragma unroll
        for (int i = 0; i < 8; ++i) {
            const float wgt = EXP2F(mp[i] - M[i]);   // log2-domain merge
            L[i] += wgt * lp[i];
            O[i] += wgt * bf2f((unsigned short)v8[i]);
        }
    }

    const float gm = gamma[0];
    const size_t xo = (size_t)bc * NPX + n0;
    float4 r0, r1;
    const float4 x0 = *(const float4*)(x + xo);
    const float4 x1 = *(const float4*)(x + xo + 4);
    r0.x = gm * O[0] / L[0] + x0.x;  r0.y = gm * O[1] / L[1] + x0.y;
    r0.z = gm * O[2] / L[2] + x0.z;  r0.w = gm * O[3] / L[3] + x0.w;
    r1.x = gm * O[4] / L[4] + x1.x;  r1.y = gm * O[5] / L[5] + x1.y;
    r1.z = gm * O[6] / L[6] + x1.z;  r1.w = gm * O[7] / L[7] + x1.w;
    *(float4*)(out + xo)     = r0;
    *(float4*)(out + xo + 4) = r1;
}

extern "C" void kernel_launch(void* const* d_in, const int* in_sizes, int n_in,
                              void* d_out, int out_size, void* d_ws, size_t ws_size,
                              hipStream_t stream)
{
    const float* x  = (const float*)d_in[0];
    const float* Wq = (const float*)d_in[1];
    const float* bq = (const float*)d_in[2];
    const float* Wk = (const float*)d_in[3];
    const float* bk = (const float*)d_in[4];
    const float* Wv = (const float*)d_in[5];
    const float* bv = (const float*)d_in[6];
    const float* gm = (const float*)d_in[7];
    float* out = (float*)d_out;
    unsigned short* ws = (unsigned short*)d_ws;

    const size_t WB_U16 = 320 * CCH;          // 81920
    const size_t BB_U16 = 320 * 2;            // 320 floats
    const size_t qkvU   = (size_t)2 * NB * NPX * 32 + (size_t)NB * CCH * NPX;
    const size_t qkvB   = (qkvU + WB_U16 + BB_U16) * 2;
    const size_t partB  = (size_t)NB * CCH * NPX * 2;                        // 8 MB / slice
    const size_t mlB    = (size_t)2 * NB * NPX * 4;                          // 128 KB / slice
    int ns = 1;
    if      (ws_size >= qkvB + 4 * (partB + mlB)) ns = 4;
    else if (ws_size >= qkvB + 2 * (partB + mlB)) ns = 2;

    unsigned short* Wb = ws + qkvU;
    float*          bb = (float*)(ws + qkvU + WB_U16);

    convert_kernel<<<320, 256, 0, stream>>>(Wq, bq, Wk, bk, Wv, bv, Wb, bb);

    // proj: 8 XCD x (32 slabs x 5 ocg) = 1280 blocks, 512 thr
    proj_mfma<<<1280, 512, 0, stream>>>(x, Wb, bb, ws);

    const unsigned short* qT = ws;
    const unsigned short* kT = ws + (size_t)NB * NPX * 32;
    const unsigned short* vB = ws + (size_t)2 * NB * NPX * 32;

    const int ablocks = NB * (NPX / BQ2) * ns;

    if (ns > 1) {
        unsigned short* opart = ws + qkvU + WB_U16 + BB_U16;
        float* mlm = (float*)(opart + (size_t)ns * NB * CCH * NPX);
        float* mll = mlm + (size_t)ns * NB * NPX;

        attn_kernel<<<ablocks, 512, 0, stream>>>(qT, kT, vB, x, gm, out,
                                                 opart, mlm, mll, ns);

        const int cblocks = (NB * CCH * (NPX / 8)) / 256;
        combine_kernel<<<cblocks, 256, 0, stream>>>(opart, mlm, mll, x, gm, out, ns);
    } else {
        attn_kernel<<<ablocks, 512, 0, stream>>>(qT, kT, vB, x, gm, out,
                                                 nullptr, nullptr, nullptr, 1);
    }
}

// Round 24
// 86.778 us; speedup vs baseline: 1.0976x; 1.0033x over previous
//
#include <hip/hip_runtime.h>
#include <hip/hip_bf16.h>
#include <cstddef>
#include <cstdint>

#define CCH 256   // channels
#define DQK 32    // q/k channels
#define NPX 4096  // H*W
#define BQ2 128   // queries per block (8 waves x 16-query strips)
#define BM  64    // key tile per iteration
#define NB  4     // batch

typedef __attribute__((ext_vector_type(8))) short bf16x8;   // 8 bf16 = 4 VGPR (MFMA A/B frag)
typedef __attribute__((ext_vector_type(4))) float f32x4;    // MFMA C/D frag
typedef __attribute__((ext_vector_type(4))) unsigned int u32x4;

#if __has_builtin(__builtin_amdgcn_exp2f)
#define EXP2F(x) __builtin_amdgcn_exp2f(x)
#else
#define EXP2F(x) exp2f(x)
#endif

__device__ inline unsigned short f2bf(float f) {            // RNE float->bf16
    unsigned u = __builtin_bit_cast(unsigned, f);
    u += 0x7FFFu + ((u >> 16) & 1u);
    return (unsigned short)(u >> 16);
}
__device__ inline float bf2f(unsigned short h) {
    unsigned u = (unsigned)h << 16;
    return __builtin_bit_cast(float, u);
}
__device__ inline unsigned pkbf(float a, float b) {         // v_cvt_pk_bf16_f32
    __hip_bfloat162 h = __float22bfloat162_rn(make_float2(a, b));
    unsigned u;
    __builtin_memcpy(&u, &h, 4);                            // a in low 16 bits
    return u;
}

// ---------------------------------------------------------------------------
// convert_kernel: W -> bf16, Wq/bq scaled by log2(e) (exp2-domain softmax).
// ---------------------------------------------------------------------------
__global__ __launch_bounds__(256) void convert_kernel(
    const float* __restrict__ Wq, const float* __restrict__ bq,
    const float* __restrict__ Wk, const float* __restrict__ bk,
    const float* __restrict__ Wv, const float* __restrict__ bv,
    unsigned short* __restrict__ Wb, float* __restrict__ bb)
{
    const float LOG2E = 1.4426950408889634f;
    const int o = blockIdx.x;
    const int c = threadIdx.x;
    float v;
    if (o < 32)       v = Wq[o * CCH + c] * LOG2E;
    else if (o < 64)  v = Wk[(o - 32) * CCH + c];
    else              v = Wv[(o - 64) * CCH + c];
    Wb[o * CCH + c] = f2bf(v);
    if (c == 0)
        bb[o] = (o < 32) ? bq[o] * LOG2E : (o < 64) ? bk[o - 32] : bv[o - 64];
}

// ---------------------------------------------------------------------------
// proj_mfma (verified R14): out[oc][px] = sum_c W[oc][c] x[c][px] + bias.
// ---------------------------------------------------------------------------
__global__ __launch_bounds__(512) void proj_mfma(
    const float* __restrict__ x,
    const unsigned short* __restrict__ Wb, const float* __restrict__ bb,
    unsigned short* __restrict__ ws)
{
    __shared__ __align__(16) unsigned short xT[64][264];   // 33 KB

    const int tid  = threadIdx.x;
    const int lane = tid & 63;
    const int w    = tid >> 6;
    const int ln   = lane & 15;
    const int g    = lane >> 4;
    const int bid  = blockIdx.x;

    const int xcd  = bid & 7;
    const int idx  = bid >> 3;             // 0..159
    const int slab = xcd + 8 * (idx / 5);  // 0..255
    const int ocg  = idx % 5;
    const int b    = slab >> 6;
    const int pxt  = slab & 63;
    const int pxg0 = pxt * 64;

    const int mt    = w >> 1;
    const int ocrow = ocg * 64 + mt * 16 + ln;
    bf16x8 a[8];
#pragma unroll
    for (int k8 = 0; k8 < 8; ++k8)
        a[k8] = *(const bf16x8*)(Wb + (size_t)ocrow * CCH + k8 * 32 + g * 8);

    {
        const int pxl = (tid & 15) * 4;
        const int c0  = (tid >> 4) * 8;
        float4 xv[8];
#pragma unroll
        for (int cc = 0; cc < 8; ++cc)
            xv[cc] = *(const float4*)(x + ((size_t)(b * CCH + c0 + cc)) * NPX + pxg0 + pxl);
#pragma unroll
        for (int j = 0; j < 4; ++j) {
            unsigned u[4];
#pragma unroll
            for (int h = 0; h < 4; ++h) {
                const float f0 = ((const float*)&xv[2 * h])[j];
                const float f1 = ((const float*)&xv[2 * h + 1])[j];
                u[h] = pkbf(f0, f1);
            }
            *(u32x4*)&xT[pxl + j][c0] = (u32x4){u[0], u[1], u[2], u[3]};
        }
    }
    __syncthreads();

    const int nt0 = (w & 1) * 2;
    const float4 bb4 = *(const float4*)(bb + ocg * 64 + mt * 16 + g * 4);
    f32x4 acc0 = (f32x4){bb4.x, bb4.y, bb4.z, bb4.w};
    f32x4 acc1 = acc0;
#pragma unroll
    for (int k8 = 0; k8 < 8; ++k8) {
        const bf16x8 b0 = *(const bf16x8*)&xT[nt0 * 16 + ln][k8 * 32 + g * 8];
        const bf16x8 b1 = *(const bf16x8*)&xT[nt0 * 16 + 16 + ln][k8 * 32 + g * 8];
        acc0 = __builtin_amdgcn_mfma_f32_16x16x32_bf16(a[k8], b0, acc0, 0, 0, 0);
        acc1 = __builtin_amdgcn_mfma_f32_16x16x32_bf16(a[k8], b1, acc1, 0, 0, 0);
    }

    unsigned short* qT = ws;
    unsigned short* kT = ws + (size_t)NB * NPX * 32;
    unsigned short* vb = ws + (size_t)2 * NB * NPX * 32;
#pragma unroll
    for (int j = 0; j < 2; ++j) {
        const f32x4 acc = j ? acc1 : acc0;
        const int px = pxg0 + (nt0 + j) * 16 + ln;
        if (ocg == 0) {
            const unsigned lo = pkbf(acc[0], acc[1]);
            const unsigned hi = pkbf(acc[2], acc[3]);
            unsigned short* dst = (mt < 2)
                ? qT + ((size_t)b * NPX + px) * 32 + mt * 16 + g * 4
                : kT + ((size_t)b * NPX + px) * 32 + (mt - 2) * 16 + g * 4;
            *(uint2*)dst = make_uint2(lo, hi);
        } else {
            const int c_row = (ocg - 1) * 64 + mt * 16 + g * 4;
#pragma unroll
            for (int rr = 0; rr < 4; ++rr)
                vb[((size_t)(b * CCH + c_row + rr)) * NPX + px] = f2bf(acc[rr]);
        }
    }
}

// ---------------------------------------------------------------------------
// Flash attention R24 = R23 (session best, 55.0us) + T5 s_setprio(1) around
// the PV MFMA cluster: with 2 blocks/CU at independent phases, priority
// favors this block's MFMA burst over the other block's softmax VALU.
// ---------------------------------------------------------------------------
__global__ __launch_bounds__(512, 4) void attn_kernel(
    const unsigned short* __restrict__ qT, const unsigned short* __restrict__ kT,
    const unsigned short* __restrict__ vB, const float* __restrict__ x,
    const float* __restrict__ gamma, float* __restrict__ out,
    unsigned short* __restrict__ opart, float* __restrict__ mlm,
    float* __restrict__ mll, int ns)
{
    __shared__ __align__(16) unsigned short Pl[2][BQ2 * 64];  // 32KB, XOR swz
    __shared__ __align__(16) unsigned short Kl[2][64 * 32];   // 8KB K stage
    __shared__ float scb[2][BQ2];
    __shared__ int   flg[2][8];
    __shared__ float l_lds[BQ2];

    const int tid  = threadIdx.x;
    const int lane = tid & 63;
    const int w    = tid >> 6;       // wave 0..7
    const int ln   = lane & 15;
    const int g    = lane >> 4;      // 16-lane group 0..3
    const int bid  = blockIdx.x;

    const int b    = (bid & 7) >> 1;                        // batch -> XCD pair
    const int jb   = ((bid >> 3) << 1) | (bid & 1);         // job in batch
    const int tile = jb / ns;
    const int s    = jb - tile * ns;
    const int n0   = tile * BQ2;

    const bf16x8 qf = *(const bf16x8*)(qT + ((size_t)b * NPX + n0 + w * 16 + ln) * 32 + g * 8);

    f32x4 acc[8][2];
#pragma unroll
    for (int qt = 0; qt < 8; ++qt) {
        acc[qt][0] = (f32x4){0.f, 0.f, 0.f, 0.f};
        acc[qt][1] = (f32x4){0.f, 0.f, 0.f, 0.f};
    }
    float mreg = -INFINITY, lreg = 0.f;

    const unsigned short* kTb = kT + (size_t)b * NPX * 32;
    const unsigned short* vb  = vB + ((size_t)b * CCH + w * 32) * NPX;
    const int kbase = s * (NPX / ns);
    const int iters = NPX / (ns * BM);
    const unsigned swz   = ((unsigned)ln & 7u) << 4;
    const unsigned myrow = (unsigned)(w * 16 + ln) * 128u;
    const float THR2 = 11.544655f;   // 8 * log2(e): P bounded by e^8

    // K DMA source pre-swizzle (involution of the read-side swizzle):
    const unsigned kdst  = (unsigned)w * 1024u + (unsigned)lane * 16u;
    const unsigned ksoff = (kdst ^ ((((unsigned)lane >> 3) & 3u) << 4)) >> 1;  // ushorts

    // ---- prologue: stage K(0) into Kl[0]
    if (w < 4) {
        const unsigned short* ksrc = kTb + (size_t)kbase * 32 + ksoff;
        __builtin_amdgcn_global_load_lds(
            (const __attribute__((address_space(1))) void*)ksrc,
            (__attribute__((address_space(3))) void*)&Kl[0][w * 512], 16, 0, 0);
    }
    asm volatile("s_waitcnt vmcnt(0)" ::: "memory");
    __syncthreads();

    for (int t = 0; t < iters; ++t) {
        const int m0 = kbase + t * BM;
        const int mnext = (t + 1 < iters) ? (m0 + BM) : m0;

        // ---- K(t+1) DMA first (waves 0-3), pinned oldest in VMEM order
        if (w < 4) {
            const unsigned short* ksrc = kTb + (size_t)mnext * 32 + ksoff;
            __builtin_amdgcn_global_load_lds(
                (const __attribute__((address_space(1))) void*)ksrc,
                (__attribute__((address_space(3))) void*)&Kl[(t + 1) & 1][w * 512], 16, 0, 0);
        }
        __builtin_amdgcn_sched_barrier(0);   // keep DMA oldest vs V loads

        // ---- E from LDS-staged K (read-side XOR swizzle: ((m>>1)&3)<<4)
        const char* kl = (const char*)&Kl[t & 1][0];
        f32x4 e[4];
#pragma unroll
        for (int s4 = 0; s4 < 4; ++s4) {
            const unsigned kb = (unsigned)(s4 * 16 + ln) * 64u + (unsigned)g * 16u;
            const bf16x8 ka = *(const bf16x8*)(kl + (kb ^ ((((unsigned)ln >> 1) & 3u) << 4)));
            e[s4] = __builtin_amdgcn_mfma_f32_16x16x32_bf16(
                        ka, qf, (f32x4){0.f, 0.f, 0.f, 0.f}, 0, 0, 0);
        }

        float lm = -INFINITY;
#pragma unroll
        for (int s4 = 0; s4 < 4; ++s4)
#pragma unroll
            for (int rr = 0; rr < 4; ++rr) lm = fmaxf(lm, e[s4][rr]);
        lm = fmaxf(lm, __shfl_xor(lm, 16));
        lm = fmaxf(lm, __shfl_xor(lm, 32));
        const float mnew = (lm <= mreg + THR2) ? mreg : lm;  // -inf -> first iter updates
        const float sc   = EXP2F(mreg - mnew);               // ==1.0 exactly when deferred
        float ps = 0.f;
#pragma unroll
        for (int s4 = 0; s4 < 4; ++s4)
#pragma unroll
            for (int rr = 0; rr < 4; ++rr) {
                const float p = EXP2F(e[s4][rr] - mnew);
                e[s4][rr] = p;
                ps += p;
            }
        ps += __shfl_xor(ps, 16);
        ps += __shfl_xor(ps, 32);
        lreg = lreg * sc + ps;
        mreg = mnew;

        const int bw = t & 1;
        char* const pwb = (char*)&Pl[bw][0];
#pragma unroll
        for (int s4 = 0; s4 < 4; ++s4) {
            uint2 pk;
            pk.x = pkbf(e[s4][0], e[s4][1]);
            pk.y = pkbf(e[s4][2], e[s4][3]);
            *(uint2*)(pwb + myrow + (((unsigned)(s4 * 32 + g * 8)) ^ swz)) = pk;
        }
        if (g == 0) scb[bw][w * 16 + ln] = sc;
        const int allsk = __all(sc == 1.0f);
        if (lane == 0) flg[bw][w] = allsk;

        // V(t) loads PRE-barrier; stay in flight across the raw barrier.
        bf16x8 va[2][2];
#pragma unroll
        for (int ct = 0; ct < 2; ++ct) {
            const unsigned short* vrow = vb + (size_t)(ct * 16 + ln) * NPX + m0 + g * 8;
            va[ct][0] = *(const bf16x8*)(vrow);
            va[ct][1] = *(const bf16x8*)(vrow + 32);
        }

        // raw barrier: drain K DMA (older than the 4 V loads) + all ds ops;
        // V loads remain outstanding. vmcnt(4) is a no-op for waves 4-7.
        asm volatile("s_waitcnt vmcnt(4) lgkmcnt(0)" ::: "memory");
        __builtin_amdgcn_s_barrier();

        int sk = flg[bw][0];
#pragma unroll
        for (int i = 1; i < 8; ++i) sk &= flg[bw][i];
        if (!sk) {
#pragma unroll
            for (int qt = 0; qt < 8; ++qt) {
                const float scq = scb[bw][qt * 16 + ln];
#pragma unroll
                for (int rr = 0; rr < 4; ++rr) {
                    acc[qt][0][rr] *= scq;
                    acc[qt][1][rr] *= scq;
                }
            }
        }
        // ---- PV MFMA cluster under raised priority (T5): favors this
        // block's matrix burst over the co-resident block's VALU phase.
        __builtin_amdgcn_s_setprio(1);
#pragma unroll
        for (int qt = 0; qt < 8; ++qt) {
            const unsigned rb = (unsigned)(qt * 16 + ln) * 128u;
            const bf16x8 pf0 = *(const bf16x8*)(pwb + rb + (((unsigned)(g * 16))      ^ swz));
            const bf16x8 pf1 = *(const bf16x8*)(pwb + rb + (((unsigned)(64 + g * 16)) ^ swz));
            acc[qt][0] = __builtin_amdgcn_mfma_f32_16x16x32_bf16(va[0][0], pf0, acc[qt][0], 0, 0, 0);
            acc[qt][0] = __builtin_amdgcn_mfma_f32_16x16x32_bf16(va[0][1], pf1, acc[qt][0], 0, 0, 0);
            acc[qt][1] = __builtin_amdgcn_mfma_f32_16x16x32_bf16(va[1][0], pf0, acc[qt][1], 0, 0, 0);
            acc[qt][1] = __builtin_amdgcn_mfma_f32_16x16x32_bf16(va[1][1], pf1, acc[qt][1], 0, 0, 0);
        }
        __builtin_amdgcn_s_setprio(0);
    }

    if (opart) {
        const size_t sb = (size_t)(s * NB + b);
#pragma unroll
        for (int qt = 0; qt < 8; ++qt)
#pragma unroll
            for (int ct = 0; ct < 2; ++ct) {
                const size_t c0 = sb * CCH + w * 32 + ct * 16 + g * 4;
#pragma unroll
                for (int rr = 0; rr < 4; ++rr)
                    opart[(c0 + rr) * NPX + n0 + qt * 16 + ln] = f2bf(acc[qt][ct][rr]);
            }
        if (g == 0) {
            mlm[sb * NPX + n0 + w * 16 + ln] = mreg;   // log2 domain
            mll[sb * NPX + n0 + w * 16 + ln] = lreg;
        }
    } else {
        if (g == 0) l_lds[w * 16 + ln] = lreg;
        __syncthreads();
        const float gm = gamma[0];
#pragma unroll
        for (int qt = 0; qt < 8; ++qt) {
            const float iv = 1.f / l_lds[qt * 16 + ln];
#pragma unroll
            for (int ct = 0; ct < 2; ++ct) {
                const size_t c0 = (size_t)b * CCH + w * 32 + ct * 16 + g * 4;
#pragma unroll
                for (int rr = 0; rr < 4; ++rr) {
                    const size_t idx = (c0 + rr) * NPX + n0 + qt * 16 + ln;
                    out[idx] = gm * acc[qt][ct][rr] * iv + x[idx];
                }
            }
        }
    }
}

// ---------------------------------------------------------------------------
// Combine: merge of ns key-slice partials (m in LOG2 domain) + residual.
// ---------------------------------------------------------------------------
__global__ __launch_bounds__(256) void combine_kernel(
    const unsigned short* __restrict__ opart,
    const float* __restrict__ mlm, const float* __restrict__ mll,
    const float* __restrict__ x, const float* __restrict__ gamma,
    float* __restrict__ out, int ns)
{
    const int idx = blockIdx.x * 256 + threadIdx.x;   // NB*CCH*512 threads
    const int bc  = idx >> 9;                          // b*CCH + c
    const int b   = bc / CCH;
    const int c   = bc - b * CCH;
    const int n0  = (idx & 511) * 8;

    float M[8];
#pragma unroll
    for (int i = 0; i < 8; ++i) M[i] = -INFINITY;
    for (int s = 0; s < ns; ++s) {
        const float* mp = mlm + ((size_t)(s * NB + b)) * NPX + n0;
#pragma unroll
        for (int i = 0; i < 8; ++i) M[i] = fmaxf(M[i], mp[i]);
    }

    float L[8], O[8];
#pragma unroll
    for (int i = 0; i < 8; ++i) { L[i] = 0.f; O[i] = 0.f; }
    for (int s = 0; s < ns; ++s) {
        const size_t sb = (size_t)(s * NB + b);
        const float* mp = mlm + sb * NPX + n0;
        const float* lp = mll + sb * NPX + n0;
        const bf16x8 v8 = *(const bf16x8*)(opart + (sb * CCH + c) * NPX + n0);
#pragma unroll
        for (int i = 0; i < 8; ++i) {
            const float wgt = EXP2F(mp[i] - M[i]);   // log2-domain merge
            L[i] += wgt * lp[i];
            O[i] += wgt * bf2f((unsigned short)v8[i]);
        }
    }

    const float gm = gamma[0];
    const size_t xo = (size_t)bc * NPX + n0;
    float4 r0, r1;
    const float4 x0 = *(const float4*)(x + xo);
    const float4 x1 = *(const float4*)(x + xo + 4);
    r0.x = gm * O[0] / L[0] + x0.x;  r0.y = gm * O[1] / L[1] + x0.y;
    r0.z = gm * O[2] / L[2] + x0.z;  r0.w = gm * O[3] / L[3] + x0.w;
    r1.x = gm * O[4] / L[4] + x1.x;  r1.y = gm * O[5] / L[5] + x1.y;
    r1.z = gm * O[6] / L[6] + x1.z;  r1.w = gm * O[7] / L[7] + x1.w;
    *(float4*)(out + xo)     = r0;
    *(float4*)(out + xo + 4) = r1;
}

extern "C" void kernel_launch(void* const* d_in, const int* in_sizes, int n_in,
                              void* d_out, int out_size, void* d_ws, size_t ws_size,
                              hipStream_t stream)
{
    const float* x  = (const float*)d_in[0];
    const float* Wq = (const float*)d_in[1];
    const float* bq = (const float*)d_in[2];
    const float* Wk = (const float*)d_in[3];
    const float* bk = (const float*)d_in[4];
    const float* Wv = (const float*)d_in[5];
    const float* bv = (const float*)d_in[6];
    const float* gm = (const float*)d_in[7];
    float* out = (float*)d_out;
    unsigned short* ws = (unsigned short*)d_ws;

    const size_t WB_U16 = 320 * CCH;          // 81920
    const size_t BB_U16 = 320 * 2;            // 320 floats
    const size_t qkvU   = (size_t)2 * NB * NPX * 32 + (size_t)NB * CCH * NPX;
    const size_t qkvB   = (qkvU + WB_U16 + BB_U16) * 2;
    const size_t partB  = (size_t)NB * CCH * NPX * 2;                        // 8 MB / slice
    const size_t mlB    = (size_t)2 * NB * NPX * 4;                          // 128 KB / slice
    int ns = 1;
    if      (ws_size >= qkvB + 4 * (partB + mlB)) ns = 4;
    else if (ws_size >= qkvB + 2 * (partB + mlB)) ns = 2;

    unsigned short* Wb = ws + qkvU;
    float*          bb = (float*)(ws + qkvU + WB_U16);

    convert_kernel<<<320, 256, 0, stream>>>(Wq, bq, Wk, bk, Wv, bv, Wb, bb);

    // proj: 8 XCD x (32 slabs x 5 ocg) = 1280 blocks, 512 thr
    proj_mfma<<<1280, 512, 0, stream>>>(x, Wb, bb, ws);

    const unsigned short* qT = ws;
    const unsigned short* kT = ws + (size_t)NB * NPX * 32;
    const unsigned short* vB = ws + (size_t)2 * NB * NPX * 32;

    const int ablocks = NB * (NPX / BQ2) * ns;

    if (ns > 1) {
        unsigned short* opart = ws + qkvU + WB_U16 + BB_U16;
        float* mlm = (float*)(opart + (size_t)ns * NB * CCH * NPX);
        float* mll = mlm + (size_t)ns * NB * NPX;

        attn_kernel<<<ablocks, 512, 0, stream>>>(qT, kT, vB, x, gm, out,
                                                 opart, mlm, mll, ns);

        const int cblocks = (NB * CCH * (NPX / 8)) / 256;
        combine_kernel<<<cblocks, 256, 0, stream>>>(opart, mlm, mll, x, gm, out, ns);
    } else {
        attn_kernel<<<ablocks, 512, 0, stream>>>(qT, kT, vB, x, gm, out,
                                                 nullptr, nullptr, nullptr, 1);
    }
}